// Round 10
// baseline (748.975 us; speedup 1.0000x reference)
//
#include <hip/hip_runtime.h>
#include <hip/hip_bf16.h>
#include <cstdint>
#include <cstddef>

// B=64, H=1024, V=32000, DEPTH=5. Harness tensors are fp32; internal compute
// bf16 MFMA + fp32 accumulate. Weights pre-converted to bf16 in ws.
// r10 = r7/r8/r9 resubmitted verbatim (r7-r9 were infra failures — the
// kernel never ran; attribution plan unchanged):
//   (1) tree 3-buffer depth-2 prefetch w/ counted VMCNT(3) + raw barrier
//   (2) logits LDS-bounce epilogue (coalesced stores, wave-row reduce)
// Logits K-loop schedule is r3's HW-proven one (unchanged).
#define H_DIM   1024
#define B_DIM   64
#define V_DIM   32000
#define DEPTH_C 5

using bf16x8  = __attribute__((ext_vector_type(8))) __bf16;
using bf16x4  = __attribute__((ext_vector_type(4))) __bf16;
using floatx4 = __attribute__((ext_vector_type(4))) float;

// async global->LDS, 16B per lane. LDS dest must be wave-uniform base + lane*16.
__device__ __forceinline__ void gl_lds16(const __bf16* g, __bf16* l) {
  __builtin_amdgcn_global_load_lds(
      (const __attribute__((address_space(1))) unsigned int*)g,
      (__attribute__((address_space(3))) unsigned int*)l, 16, 0, 0);
}

// grid-stride fp32 -> bf16 (n % 4 == 0)
__global__ __launch_bounds__(256) void f2b(const float* __restrict__ in,
                                           __bf16* __restrict__ out, int n) {
  for (int i = (blockIdx.x * 256 + threadIdx.x) * 4; i < n;
       i += gridDim.x * 1024) {
    float4 v = *(const float4*)(in + i);
    bf16x4 o;
    o[0] = (__bf16)v.x; o[1] = (__bf16)v.y; o[2] = (__bf16)v.z; o[3] = (__bf16)v.w;
    *(bf16x4*)(out + i) = o;
  }
}

__device__ __forceinline__ bf16x8 cvt8(float4 a, float4 b) {
  bf16x8 r;
  r[0] = (__bf16)a.x; r[1] = (__bf16)a.y; r[2] = (__bf16)a.z; r[3] = (__bf16)a.w;
  r[4] = (__bf16)b.x; r[5] = (__bf16)b.y; r[6] = (__bf16)b.z; r[7] = (__bf16)b.w;
  return r;
}

// ===========================================================================
// Logits GEMM, 256x256 8-wave schedule (T1+T2+T3+T4+T5):
//   C[2048,32000] = A[2048,1024](bf16) * W[32000,1024](bf16)^T + bias
//   + fused per-row (max, sum exp) partials over each 256-col block.
// K-loop: r3's HW-proven counted-vmcnt phase schedule (see r3 notes).
// Epilogue: dump biased acc -> LDS [128][256] fp32 with granule XOR-swizzle
// (write 2-way = free; read distinct-granule = conflict-free), then
// wave-per-row readback: 1KB contiguous store per wave-row + 6-step
// full-wave shfl (max, sum exp). Two halves (wr=0 rows 0..127, wr=1 128..255).
// ===========================================================================
#define VMCNT(n) asm volatile("s_waitcnt vmcnt(" #n ")" ::: "memory")
#define LGK0()                                  \
  do {                                          \
    asm volatile("s_waitcnt lgkmcnt(0)" ::: "memory"); \
    __builtin_amdgcn_sched_barrier(0);          \
  } while (0)
#define SBAR()                                  \
  do {                                          \
    __builtin_amdgcn_sched_barrier(0);          \
    __builtin_amdgcn_s_barrier();               \
    __builtin_amdgcn_sched_barrier(0);          \
  } while (0)
#define LDA(MH, KS)                                                          \
  do {                                                                       \
    _Pragma("unroll") for (int mf = 0; mf < 4; ++mf)                         \
        aF[mf] = *(const bf16x8*)(cb + aRow + (MH)*8192 + mf * 2048 +        \
                                  ((KS) ? cksw1 : cksw0));                   \
  } while (0)
#define LDB(KS)                                                              \
  do {                                                                       \
    _Pragma("unroll") for (int nj = 0; nj < 4; ++nj)                         \
        bB[nj] = *(const bf16x8*)(cb + 32768 + bRow + nj * 2048 +            \
                                  ((KS) ? cksw1 : cksw0));                   \
  } while (0)
#define MM(MH)                                                               \
  do {                                                                       \
    __builtin_amdgcn_s_setprio(1);                                           \
    _Pragma("unroll") for (int mf = 0; mf < 4; ++mf)                         \
        _Pragma("unroll") for (int nj = 0; nj < 4; ++nj)                     \
            acc[(MH)*4 + mf][nj] = __builtin_amdgcn_mfma_f32_16x16x32_bf16(  \
                aF[mf], bB[nj], acc[(MH)*4 + mf][nj], 0, 0, 0);              \
    __builtin_amdgcn_s_setprio(0);                                           \
  } while (0)

__global__ __launch_bounds__(512, 2) void gemm_logits_8ph(
    const __bf16* __restrict__ A, const __bf16* __restrict__ Wb,
    float* __restrict__ Cf, const float* __restrict__ bias,
    float2* __restrict__ part) {
  __shared__ __align__(16) char smem[131072];

  const int tid = threadIdx.x;
  // T1 bijective XCD swizzle: grid (8,125), nwg=1000 % 8 == 0.
  int h = blockIdx.y * 8 + blockIdx.x;
  h = (h & 7) * 125 + (h >> 3);
  const int bx = h & 7, by = h >> 3;
  const int m0 = bx * 256, n0 = by * 256;

  const int lane = tid & 63, wave = tid >> 6;
  const int wr = wave >> 2, wc = wave & 3;     // 2M x 4N waves
  const int lrow = lane & 15, quad = lane >> 4;

  // frag-read bases (byte offsets into a 64KB buffer half)
  const int aRow  = (wr * 128 + lrow) * 128;
  const int bRow  = (wc * 64 + lrow) * 128;
  const int lsw   = (lrow & 7) << 4;
  const int cksw0 = (quad * 16) ^ lsw;         // kslice 0
  const int cksw1 = (64 + quad * 16) ^ lsw;    // kslice 1

  // staging: thread covers chunk row = base + (tid>>3), 16B slot ci = tid&7.
  // Pre-swizzled source column: cix = ci ^ (row&7).
  const int t8  = tid >> 3;
  const int cix = (tid & 7) ^ (t8 & 7);
  const __bf16* gA00 = A + (size_t)(m0 + t8) * 1024 + cix * 8;
  const __bf16* gA01 = A + (size_t)(m0 + 128 + t8) * 1024 + cix * 8;
  const __bf16* gA10 = gA00 + 64 * 1024;
  const __bf16* gA11 = gA01 + 64 * 1024;
  const __bf16* gB00 = Wb + (size_t)(n0 + t8) * 1024 + cix * 8;
  const __bf16* gB01 = Wb + (size_t)(n0 + 64 + t8) * 1024 + cix * 8;
  const __bf16* gB10 = gB00 + 128 * 1024;
  const __bf16* gB11 = gB01 + 128 * 1024;

  floatx4 acc[8][4] = {};
  bf16x8 aF[4], bB[4];

  // prologue: stage tile 0 into buf0, order A0,B*,A1 (first 6 = P1's needs).
  gl_lds16(gA00, (__bf16*)(smem + tid * 16));
  gl_lds16(gA01, (__bf16*)(smem + 16384 + tid * 16));
  gl_lds16(gB00, (__bf16*)(smem + 32768 + tid * 16));
  gl_lds16(gB01, (__bf16*)(smem + 40960 + tid * 16));
  gl_lds16(gB10, (__bf16*)(smem + 49152 + tid * 16));
  gl_lds16(gB11, (__bf16*)(smem + 57344 + tid * 16));
  gl_lds16(gA10, (__bf16*)(smem + 8192 + tid * 16));
  gl_lds16(gA11, (__bf16*)(smem + 24576 + tid * 16));
  VMCNT(2);   // A0 + all B resident; A1 still in flight
  SBAR();

  for (int t = 0; t < 15; ++t) {
    char* cb = smem + (t & 1) * 65536;
    char* nb = smem + ((t & 1) ^ 1) * 65536;
    const int ke = (t + 1) * 64;
    // P1 (mh0,k0)
    LDB(0); LDA(0, 0);
    gl_lds16(gA00 + ke, (__bf16*)(nb + tid * 16));
    gl_lds16(gA01 + ke, (__bf16*)(nb + 16384 + tid * 16));
    SBAR(); LGK0();
    MM(0);
    VMCNT(2); SBAR();         // retire A1^t, publish for P2
    // P2 (mh1,k0)
    LDA(1, 0);
    gl_lds16(gB00 + ke, (__bf16*)(nb + 32768 + tid * 16));
    gl_lds16(gB01 + ke, (__bf16*)(nb + 40960 + tid * 16));
    SBAR(); LGK0();
    MM(1);
    SBAR();
    // P3 (mh0,k1)
    LDB(1); LDA(0, 1);
    gl_lds16(gB10 + ke, (__bf16*)(nb + 49152 + tid * 16));
    gl_lds16(gB11 + ke, (__bf16*)(nb + 57344 + tid * 16));
    SBAR(); LGK0();
    MM(0);
    SBAR();
    // P4 (mh1,k1)
    LDA(1, 1);
    gl_lds16(gA10 + ke, (__bf16*)(nb + 8192 + tid * 16));
    gl_lds16(gA11 + ke, (__bf16*)(nb + 24576 + tid * 16));
    SBAR(); LGK0();
    MM(1);
    VMCNT(2); SBAR();         // retire next tile's A0+B, publish for its P1
  }
  {  // last K-tile (buf1): only A1^15 outstanding; drain it before mh1.
    char* cb = smem + 65536;
    LDB(0); LDA(0, 0); MM(0);
    VMCNT(0); SBAR();
    LDA(1, 0); MM(1);
    LDB(1); LDA(0, 1); MM(0);
    LDA(1, 1); MM(1);
  }

  // ---- epilogue: LDS bounce -> coalesced stores + softmax partials ------
  // C/D layout: col = lane&15, row = quad*4 + reg  [m89-verified]
  float bv[4];
#pragma unroll
  for (int nj = 0; nj < 4; ++nj) bv[nj] = bias[n0 + wc * 64 + nj * 16 + lrow];

  float* lf = (float*)smem;   // [128][256] fp32, granule-swizzled

  __syncthreads();            // all waves done with K-loop LDS reads
#pragma unroll
  for (int half = 0; half < 2; ++half) {
    if (half) __syncthreads();   // half-0 readers done before half-1 dump
    if (wr == half) {
      // dump biased acc. write: per instr, 2 lanes/bank (free).
#pragma unroll
      for (int mi = 0; mi < 8; ++mi) {
#pragma unroll
        for (int nj = 0; nj < 4; ++nj) {
          const int colg = wc * 16 + nj * 4 + (lrow >> 2);
          const int cole = lrow & 3;
#pragma unroll
          for (int r = 0; r < 4; ++r) {
            const int rowL = mi * 16 + quad * 4 + r;
            lf[rowL * 256 + ((colg ^ (rowL & 7)) << 2) + cole] =
                acc[mi][nj][r] + bv[nj];
          }
        }
      }
    }
    __syncthreads();
    // wave-per-row readback: wave handles rows {it*8+wave}, lane l owns
    // cols [4l, 4l+4). Store is 1KB contiguous per wave-row.
#pragma unroll
    for (int it = 0; it < 16; ++it) {
      const int rowL = it * 8 + wave;
      const int rsw  = rowL & 7;
      const float4 v =
          *(const float4*)&lf[rowL * 256 + ((lane ^ rsw) << 2)];
      const int grow = m0 + half * 128 + rowL;
      *(float4*)(Cf + (size_t)grow * V_DIM + n0 + lane * 4) = v;
      float mx = fmaxf(fmaxf(v.x, v.y), fmaxf(v.z, v.w));
#pragma unroll
      for (int off = 32; off; off >>= 1) mx = fmaxf(mx, __shfl_xor(mx, off, 64));
      float sm = __expf(v.x - mx) + __expf(v.y - mx) + __expf(v.z - mx) +
                 __expf(v.w - mx);
#pragma unroll
      for (int off = 32; off; off >>= 1) sm += __shfl_xor(sm, off, 64);
      if (lane == 0)
        part[(size_t)grow * gridDim.y + by] = make_float2(mx, sm);
    }
  }
}

// ---------------------------------------------------------------------------
// Tree-level GEMM: gh[M,6144] = h[M,1024] * Whh[6144,1024]^T (all bf16).
// Tile 128x64, 256 thr (4 waves stacked in M), BK=32.
// Depth-2 prefetch, 3-buffer round-robin, counted VMCNT(3) + RAW barrier
// (no vmcnt(0) drain in the loop — that drain was the m97-style stall).
// Ledger (per wave): enter iter t with 6 outstanding (tiles t, t+1);
// VMCNT(3) retires tile t's 3; SBAR -> every wave retired tile t -> whole
// tile resident. Write-after-read: buf (t+2)%3 was read at iter t-1; those
// ds_reads complete before each wave's MFMAs issue (compiler lgkmcnt),
// hence before it reaches iter t's SBAR; TSTAGE is issued after the SBAR.
// W split left|right at n=3072.
// ---------------------------------------------------------------------------
__global__ __launch_bounds__(256) void gemm_tree(
    const __bf16* __restrict__ A, const __bf16* __restrict__ Wb0,
    const __bf16* __restrict__ Wb1, __bf16* __restrict__ Cb, int M) {
  constexpr int K = H_DIM;
  __shared__ __align__(16) __bf16 As[3][128 * 32];
  __shared__ __align__(16) __bf16 Bs[3][64 * 32];

  const int tid = threadIdx.x;
  const int nbx = gridDim.x;
  const int nwg = nbx * gridDim.y;
  int hflat = blockIdx.y * nbx + blockIdx.x;
  if ((nwg & 7) == 0) {
    const int cpx = nwg >> 3;
    hflat = (hflat & 7) * cpx + (hflat >> 3);
  }
  const int bx = hflat % nbx;
  const int by = hflat / nbx;
  const int m0 = bx * 128;
  const int n0 = by * 64;
  const int lane = tid & 63, wave = tid >> 6;
  const int lrow = lane & 15, quad = lane >> 4;
  const int wm = wave * 32;

  const __bf16* Wb = Wb0;
  int nw0 = n0;
  if (n0 >= 3072) { Wb = Wb1; nw0 = n0 - 3072; }

  const int sr = tid >> 2;       // 0..63
  const int sk = (tid & 3) * 8;  // 0,8,16,24
  int ra0 = m0 + sr;      if (ra0 >= M) ra0 = M - 1;  // clamp (small M)
  int ra1 = m0 + sr + 64; if (ra1 >= M) ra1 = M - 1;
  const __bf16* ga0 = A + (size_t)ra0 * K + sk;
  const __bf16* ga1 = A + (size_t)ra1 * K + sk;
  const __bf16* gb0 = Wb + (size_t)(nw0 + sr) * K + sk;

  floatx4 acc[2][4] = {};

#define TSTAGE(T, BUF)                                     \
  do {                                                     \
    gl_lds16(ga0 + (T) * 32, As[BUF] + tid * 8);           \
    gl_lds16(ga1 + (T) * 32, As[BUF] + 2048 + tid * 8);    \
    gl_lds16(gb0 + (T) * 32, Bs[BUF] + tid * 8);           \
  } while (0)
#define TCOMP(CB)                                                            \
  do {                                                                       \
    bf16x8 af[2], bfr[4];                                                    \
    _Pragma("unroll") for (int i = 0; i < 2; i++)                            \
        af[i] = *(const bf16x8*)(&As[CB][(wm + i * 16 + lrow) * 32 +         \
                                         quad * 8]);                         \
    _Pragma("unroll") for (int j = 0; j < 4; j++)                            \
        bfr[j] = *(const bf16x8*)(&Bs[CB][(j * 16 + lrow) * 32 + quad * 8]); \
    _Pragma("unroll") for (int i = 0; i < 2; i++)                            \
        _Pragma("unroll") for (int j = 0; j < 4; j++)                        \
            acc[i][j] = __builtin_amdgcn_mfma_f32_16x16x32_bf16(             \
                af[i], bfr[j], acc[i][j], 0, 0, 0);                          \
  } while (0)

  TSTAGE(0, 0);
  TSTAGE(1, 1);
  for (int t = 0; t < 31; ++t) {
    VMCNT(3);          // tile t resident (tile t+1's 3 loads stay in flight)
    SBAR();            // all waves retired tile t; buf (t+2)%3 free
    if (t + 2 < 32) TSTAGE(t + 2, (t + 2) % 3);
    TCOMP(t % 3);
  }
  VMCNT(0);
  SBAR();
  TCOMP(31 % 3);
#undef TSTAGE
#undef TCOMP

  // C/D layout: col = lane&15, row = quad*4 + reg
#pragma unroll
  for (int i = 0; i < 2; i++) {
#pragma unroll
    for (int j = 0; j < 4; j++) {
      const int col = n0 + j * 16 + lrow;
#pragma unroll
      for (int r = 0; r < 4; r++) {
        const int row = m0 + wm + i * 16 + quad * 4 + r;
        if (row < M) Cb[(size_t)row * 6144 + col] = (__bf16)acc[i][j][r];
      }
    }
  }
}

// ---------------------------------------------------------------------------
// NT GEMM fallback (logits path when ws too small for bf16 W_out).
// ---------------------------------------------------------------------------
template <int TN, bool LOGITS, bool WBF16>
__global__ __launch_bounds__(256) void gemm_nt(
    const __bf16* __restrict__ A, const __bf16* __restrict__ Wb0,
    const __bf16* __restrict__ Wb1, const float* __restrict__ Wf,
    __bf16* __restrict__ Cb, float* __restrict__ Cf,
    const float* __restrict__ bias, float2* __restrict__ part, int M, int N) {
  constexpr int K = H_DIM;
  constexpr int MI = (TN == 128) ? 4 : 2;
  __shared__ __align__(16) __bf16 As[128 * 32];
  __shared__ __align__(16) __bf16 Bs[TN * 32];

  const int tid  = threadIdx.x;
  const int nbx = gridDim.x;
  const int nwg = nbx * gridDim.y;
  int hflat = blockIdx.y * nbx + blockIdx.x;
  if ((nwg & 7) == 0) {
    const int cpx = nwg >> 3;
    hflat = (hflat & 7) * cpx + (hflat >> 3);
  }
  const int bx = hflat % nbx;
  const int by = hflat / nbx;
  const int m0   = bx * 128;
  const int n0   = by * TN;
  const int lane = tid & 63;
  const int wave = tid >> 6;
  const int lrow = lane & 15;
  const int quad = lane >> 4;
  const int wm   = (TN == 128) ? (wave >> 1) * 64 : wave * 32;
  const int wn   = (TN == 128) ? (wave & 1) * 64 : 0;

  const __bf16* Wb = Wb0;
  int nw0 = n0;
  if (!LOGITS && n0 >= 3072) { Wb = Wb1; nw0 = n0 - 3072; }

  const int sr = tid >> 2;
  const int sk = (tid & 3) * 8;

  int ra0 = m0 + sr;      if (ra0 >= M) ra0 = M - 1;
  int ra1 = m0 + sr + 64; if (ra1 >= M) ra1 = M - 1;
  const __bf16* ga0 = A + (size_t)ra0 * K + sk;
  const __bf16* ga1 = A + (size_t)ra1 * K + sk;
  const __bf16* gb0 = nullptr; const __bf16* gb1 = nullptr;
  const float* gf0 = nullptr; const float* gf1 = nullptr;
  if (WBF16) {
    gb0 = Wb + (size_t)(nw0 + sr) * K + sk;
    if (TN == 128) gb1 = Wb + (size_t)(nw0 + sr + 64) * K + sk;
  } else {
    gf0 = Wf + (size_t)(n0 + sr) * K + sk;
    gf1 = Wf + (size_t)(n0 + sr + 64) * K + sk;
  }

  floatx4 acc[MI][4] = {};

  for (int kt = 0; kt < K; kt += 32) {
    float4 w00, w01, w10, w11;
    if (!WBF16) {
      w00 = *(const float4*)(gf0 + kt);
      w01 = *(const float4*)(gf0 + kt + 4);
      w10 = *(const float4*)(gf1 + kt);
      w11 = *(const float4*)(gf1 + kt + 4);
    }
    __syncthreads();
    gl_lds16(ga0 + kt, As + tid * 8);
    gl_lds16(ga1 + kt, As + 2048 + tid * 8);
    if (WBF16) {
      gl_lds16(gb0 + kt, Bs + tid * 8);
      if (TN == 128) gl_lds16(gb1 + kt, Bs + 2048 + tid * 8);
    } else {
      *(bf16x8*)(&Bs[sr * 32 + sk])        = cvt8(w00, w01);
      *(bf16x8*)(&Bs[(sr + 64) * 32 + sk]) = cvt8(w10, w11);
    }
    __syncthreads();

    bf16x8 af[MI], bfr[4];
#pragma unroll
    for (int i = 0; i < MI; i++)
      af[i] = *(const bf16x8*)(&As[(wm + i * 16 + lrow) * 32 + quad * 8]);
#pragma unroll
    for (int j = 0; j < 4; j++)
      bfr[j] = *(const bf16x8*)(&Bs[(wn + j * 16 + lrow) * 32 + quad * 8]);
#pragma unroll
    for (int i = 0; i < MI; i++)
#pragma unroll
      for (int j = 0; j < 4; j++)
        acc[i][j] =
            __builtin_amdgcn_mfma_f32_16x16x32_bf16(af[i], bfr[j], acc[i][j], 0, 0, 0);
  }

  float bv[4];
  if constexpr (LOGITS) {
#pragma unroll
    for (int j = 0; j < 4; j++) bv[j] = bias[n0 + wn + j * 16 + lrow];
  }
#pragma unroll
  for (int i = 0; i < MI; i++) {
#pragma unroll
    for (int j = 0; j < 4; j++) {
      const int col = n0 + wn + j * 16 + lrow;
#pragma unroll
      for (int r = 0; r < 4; r++) {
        const int row = m0 + wm + i * 16 + quad * 4 + r;
        if (row < M) {
          if (LOGITS) Cf[(size_t)row * N + col] = acc[i][j][r] + bv[j];
          else        Cb[(size_t)row * N + col] = (__bf16)acc[i][j][r];
        }
      }
    }
  }

  if constexpr (LOGITS) {
    __shared__ float pmax[2][128], psum[2][128];
    const int wnh = wn >> 6;
#pragma unroll
    for (int i = 0; i < MI; i++) {
#pragma unroll
      for (int r = 0; r < 4; r++) {
        float mx = -3.0e38f;
#pragma unroll
        for (int j = 0; j < 4; j++) mx = fmaxf(mx, acc[i][j][r] + bv[j]);
#pragma unroll
        for (int mask = 1; mask < 16; mask <<= 1)
          mx = fmaxf(mx, __shfl_xor(mx, mask, 64));
        float sm = 0.f;
#pragma unroll
        for (int j = 0; j < 4; j++) sm += __expf(acc[i][j][r] + bv[j] - mx);
#pragma unroll
        for (int mask = 1; mask < 16; mask <<= 1)
          sm += __shfl_xor(sm, mask, 64);
        if (lrow == 0) {
          pmax[wnh][wm + i * 16 + quad * 4 + r] = mx;
          psum[wnh][wm + i * 16 + quad * 4 + r] = sm;
        }
      }
    }
    __syncthreads();
    if (tid < 128) {
      const float ma = pmax[0][tid], mb = pmax[1][tid];
      const float nm = fmaxf(ma, mb);
      const float ns = psum[0][tid] * __expf(ma - nm) +
                       psum[1][tid] * __expf(mb - nm);
      part[(size_t)(m0 + tid) * gridDim.y + by] = make_float2(nm, ns);
    }
  }
}

// ---------------------------------------------------------------------------
// GRU gates from gh (M x 6144 bf16, [left 3H | right 3H], no biases in gh).
// Vectorized x4 (G13). grid = (M), block 256, thread handles 4 cols.
// children interleaved: left -> 2j, right -> 2j+1.
// ---------------------------------------------------------------------------
__global__ __launch_bounds__(256) void gru_gate(
    const __bf16* __restrict__ gh, const float* __restrict__ bih_l,
    const float* __restrict__ bhh_l, const float* __restrict__ bih_r,
    const float* __restrict__ bhh_r, const __bf16* __restrict__ hin,
    __bf16* __restrict__ hout, int n) {
  const int row = blockIdx.x;
  const int c = threadIdx.x * 4;
  const int b = row / n, j = row - b * n;
  const size_t g6 = (size_t)row * 6144;
  const bf16x4 h4 = *(const bf16x4*)(hin + (size_t)row * H_DIM + c);
  const size_t obase = (size_t)(b * 2 * n + 2 * j) * H_DIM;

  bf16x4 og[2];
#pragma unroll
  for (int side = 0; side < 2; ++side) {
    const float* bih = side ? bih_r : bih_l;
    const float* bhh = side ? bhh_r : bhh_l;
    const size_t gb = g6 + side * 3072;
    const bf16x4 g0 = *(const bf16x4*)(gh + gb + c);
    const bf16x4 g1 = *(const bf16x4*)(gh + gb + 1024 + c);
    const bf16x4 g2 = *(const bf16x4*)(gh + gb + 2048 + c);
    const float4 br0 = *(const float4*)(bih + c);
    const float4 br1 = *(const float4*)(bih + 1024 + c);
    const float4 br2 = *(const float4*)(bih + 2048 + c);
    const float4 bh0 = *(const float4*)(bhh + c);
    const float4 bh1 = *(const float4*)(bhh + 1024 + c);
    const float4 bh2 = *(const float4*)(bhh + 2048 + c);
    const float* pr0 = (const float*)&br0; const float* ph0 = (const float*)&bh0;
    const float* pr1 = (const float*)&br1; const float* ph1 = (const float*)&bh1;
    const float* pr2 = (const float*)&br2; const float* ph2 = (const float*)&bh2;
    bf16x4 o;
#pragma unroll
    for (int e = 0; e < 4; ++e) {
      const float gr = (float)g0[e] + ph0[e];
      const float gz = (float)g1[e] + ph1[e];
      const float gn = (float)g2[e] + ph2[e];
      const float r = 1.f / (1.f + __expf(-(pr0[e] + gr)));
      const float z = 1.f / (1.f + __expf(-(pr1[e] + gz)));
      const float nn = tanhf(pr2[e] + r * gn);
      o[e] = (__bf16)((1.f - z) * nn + z * (float)h4[e]);
    }
    og[side] = o;
  }
  *(bf16x4*)(hout + obase + c) = og[0];
  *(bf16x4*)(hout + obase + H_DIM + c) = og[1];
}

// ---------------------------------------------------------------------------
// log_softmax finish: reduce NB per-row (max,sum) partials, then one RMW pass.
// ---------------------------------------------------------------------------
__global__ __launch_bounds__(256) void lsm_finish(
    float* __restrict__ out, const float2* __restrict__ part, int nb) {
  const int row = blockIdx.x;
  const int tid = threadIdx.x;

  float m = -3.0e38f, s = 0.f;
  if (tid < nb) {
    const float2 p = part[(size_t)row * nb + tid];
    m = p.x; s = p.y;
  }
#pragma unroll
  for (int off = 32; off; off >>= 1) {
    float om = __shfl_xor(m, off, 64);
    float os = __shfl_xor(s, off, 64);
    float nm = fmaxf(m, om);
    s = s * __expf(m - nm) + os * __expf(om - nm);
    m = nm;
  }
  __shared__ float rm[4], rs[4];
  if ((tid & 63) == 0) { rm[tid >> 6] = m; rs[tid >> 6] = s; }
  __syncthreads();
  const float M4 = fmaxf(fmaxf(rm[0], rm[1]), fmaxf(rm[2], rm[3]));
  const float S4 = rs[0] * __expf(rm[0] - M4) + rs[1] * __expf(rm[1] - M4) +
                   rs[2] * __expf(rm[2] - M4) + rs[3] * __expf(rm[3] - M4);
  const float lg = M4 + __logf(S4);

  float4* p4 = (float4*)(out + (size_t)row * V_DIM);
  for (int i = tid; i < 8000; i += 256) {
    float4 v = p4[i];
    v.x -= lg; v.y -= lg; v.z -= lg; v.w -= lg;
    p4[i] = v;
  }
}

// ---------------------------------------------------------------------------
extern "C" void kernel_launch(void* const* d_in, const int* in_sizes, int n_in,
                              void* d_out, int out_size, void* d_ws,
                              size_t ws_size, hipStream_t stream) {
  const float* enc   = (const float*)d_in[0];
  const float* Whh_l = (const float*)d_in[1];
  const float* bih_l = (const float*)d_in[2];
  const float* bhh_l = (const float*)d_in[3];
  const float* Whh_r = (const float*)d_in[4];
  const float* bih_r = (const float*)d_in[5];
  const float* bhh_r = (const float*)d_in[6];
  const float* W_out = (const float*)d_in[7];
  const float* b_out = (const float*)d_in[8];
  float* out = (float*)d_out;

  char* ws = (char*)d_ws;
  __bf16* ghb    = (__bf16*)ws;                          // 12,582,912
  __bf16* buf0   = (__bf16*)(ws + 12582912);             // 4 MB
  __bf16* buf1   = (__bf16*)(ws + 16777216);             // 4 MB
  __bf16* WhhB_l = (__bf16*)(ws + 20971520);             // 6,291,456
  __bf16* WhhB_r = WhhB_l + 3145728;                     // 6,291,456
  __bf16* encB   = (__bf16*)(ws + 33554432);             // 131,072
  __bf16* WoutB  = (__bf16*)(ws + 33685504);             // 65,536,000
  float2* part   = (float2*)ghb;                         // ghb dead by logits
  const bool big = ws_size >= (size_t)(33685504 + 65536000);

  f2b<<<256, 256, 0, stream>>>(Whh_l, WhhB_l, 3 * H_DIM * H_DIM);
  f2b<<<256, 256, 0, stream>>>(Whh_r, WhhB_r, 3 * H_DIM * H_DIM);
  f2b<<<64, 256, 0, stream>>>(enc, encB, B_DIM * H_DIM);
  if (big) f2b<<<1024, 256, 0, stream>>>(W_out, WoutB, V_DIM * H_DIM);

  const __bf16* cur = encB;
  __bf16* nxt = buf0;
  int n = 1;
  for (int d = 0; d < DEPTH_C; d++) {
    const int M = B_DIM * n;
    dim3 gg((M + 127) / 128, 6144 / 64);
    gemm_tree<<<gg, 256, 0, stream>>>(cur, WhhB_l, WhhB_r, ghb, M);
    gru_gate<<<dim3(M), 256, 0, stream>>>(ghb, bih_l, bhh_l, bih_r, bhh_r,
                                          cur, nxt, n);
    cur = nxt;
    nxt = (nxt == buf0) ? buf1 : buf0;
    n *= 2;
  }

  // logits = cur(2048x1024 bf16) @ W_out^T + b_out -> d_out fp32 (+ partials)
  if (big) {
    gemm_logits_8ph<<<dim3(8, 125), 512, 0, stream>>>(cur, WoutB, out, b_out,
                                                      part);
    lsm_finish<<<2048, 256, 0, stream>>>(out, part, 125);
  } else {
    dim3 gf(2048 / 128, V_DIM / 128);
    gemm_nt<128, true, false><<<gf, 256, 0, stream>>>(
        cur, nullptr, nullptr, W_out, nullptr, out, b_out, part, 2048, V_DIM);
    lsm_finish<<<2048, 256, 0, stream>>>(out, part, 250);
  }
}

// Round 13
// 723.654 us; speedup vs baseline: 1.0350x; 1.0350x over previous
//
#include <hip/hip_runtime.h>
#include <hip/hip_bf16.h>
#include <cstdint>
#include <cstddef>

// B=64, H=1024, V=32000, DEPTH=5. Harness tensors are fp32; internal compute
// bf16 MFMA + fp32 accumulate. Weights pre-converted to bf16 in ws.
// r13 = r11/r12 resubmitted verbatim (both were GPUAcquisitionTimeout — the
// kernel never ran; attribution plan unchanged):
//   - REVERT logits LDS-bounce epilogue -> r3's proven shfl-ladder epilogue
//     (r10 measured: bounce +57us, serial 12-shfl chains; r3 ladders have ILP)
//   - KEEP tree 3-buffer counted-VMCNT prefetch (r10 measured: -50us)
//   - ADD staggered-vmcnt logits K-loop (audited r4 change): stage
//     A0'+B0'@P1, B1'@P2, A1'@P3, none@P4 -> every retired load has
//     >=2 phases of flight margin (P1 waits VMCNT(4), P4 waits VMCNT(2)).
#define H_DIM   1024
#define B_DIM   64
#define V_DIM   32000
#define DEPTH_C 5

using bf16x8  = __attribute__((ext_vector_type(8))) __bf16;
using bf16x4  = __attribute__((ext_vector_type(4))) __bf16;
using floatx4 = __attribute__((ext_vector_type(4))) float;

// async global->LDS, 16B per lane. LDS dest must be wave-uniform base + lane*16.
__device__ __forceinline__ void gl_lds16(const __bf16* g, __bf16* l) {
  __builtin_amdgcn_global_load_lds(
      (const __attribute__((address_space(1))) unsigned int*)g,
      (__attribute__((address_space(3))) unsigned int*)l, 16, 0, 0);
}

// grid-stride fp32 -> bf16 (n % 4 == 0)
__global__ __launch_bounds__(256) void f2b(const float* __restrict__ in,
                                           __bf16* __restrict__ out, int n) {
  for (int i = (blockIdx.x * 256 + threadIdx.x) * 4; i < n;
       i += gridDim.x * 1024) {
    float4 v = *(const float4*)(in + i);
    bf16x4 o;
    o[0] = (__bf16)v.x; o[1] = (__bf16)v.y; o[2] = (__bf16)v.z; o[3] = (__bf16)v.w;
    *(bf16x4*)(out + i) = o;
  }
}

__device__ __forceinline__ bf16x8 cvt8(float4 a, float4 b) {
  bf16x8 r;
  r[0] = (__bf16)a.x; r[1] = (__bf16)a.y; r[2] = (__bf16)a.z; r[3] = (__bf16)a.w;
  r[4] = (__bf16)b.x; r[5] = (__bf16)b.y; r[6] = (__bf16)b.z; r[7] = (__bf16)b.w;
  return r;
}

// ===========================================================================
// Logits GEMM, 256x256 8-wave schedule (T1+T2+T3+T4+T5):
//   C[2048,32000] = A[2048,1024](bf16) * W[32000,1024](bf16)^T + bias
//   + fused per-row (max, sum exp) partials over each 256-col block.
// T2: global_load_lds w16, LINEAR LDS dest + PRE-SWIZZLED global source;
// reads XOR byte^((row&7)<<4) -> conflict-free ds_read_b128 (r2-verified 0).
// Staggered counted-vmcnt: stage A0',B0'@P1, B1'@P2, A1'@P3, none@P4.
//   Entering P1 of tile t: outstanding [A1^t] (2 loads).
//   P1 issues A0'+B0' (6 out), VMCNT(4) retires A1^t — issued P3 of t-1,
//     2-phase margin; P1 trailing SBAR publishes for P2's LDA(1,0).
//   P2 issues B1' (6 out). P3 issues A1' (8 out). P4 stages nothing;
//   VMCNT(2) retires A0',B0',B1' — youngest B1' issued P2, 2-phase margin;
//   trailing SBAR publishes next tile's P1 data. Never vmcnt(0) in loop.
// Epilogue: r3's HW-proven shfl-ladder form (32 independent 4-step ladders).
// ===========================================================================
#define VMCNT(n) asm volatile("s_waitcnt vmcnt(" #n ")" ::: "memory")
#define LGK0()                                  \
  do {                                          \
    asm volatile("s_waitcnt lgkmcnt(0)" ::: "memory"); \
    __builtin_amdgcn_sched_barrier(0);          \
  } while (0)
#define SBAR()                                  \
  do {                                          \
    __builtin_amdgcn_sched_barrier(0);          \
    __builtin_amdgcn_s_barrier();               \
    __builtin_amdgcn_sched_barrier(0);          \
  } while (0)
#define LDA(MH, KS)                                                          \
  do {                                                                       \
    _Pragma("unroll") for (int mf = 0; mf < 4; ++mf)                         \
        aF[mf] = *(const bf16x8*)(cb + aRow + (MH)*8192 + mf * 2048 +        \
                                  ((KS) ? cksw1 : cksw0));                   \
  } while (0)
#define LDB(KS)                                                              \
  do {                                                                       \
    _Pragma("unroll") for (int nj = 0; nj < 4; ++nj)                         \
        bB[nj] = *(const bf16x8*)(cb + 32768 + bRow + nj * 2048 +            \
                                  ((KS) ? cksw1 : cksw0));                   \
  } while (0)
#define MM(MH)                                                               \
  do {                                                                       \
    __builtin_amdgcn_s_setprio(1);                                           \
    _Pragma("unroll") for (int mf = 0; mf < 4; ++mf)                         \
        _Pragma("unroll") for (int nj = 0; nj < 4; ++nj)                     \
            acc[(MH)*4 + mf][nj] = __builtin_amdgcn_mfma_f32_16x16x32_bf16(  \
                aF[mf], bB[nj], acc[(MH)*4 + mf][nj], 0, 0, 0);              \
    __builtin_amdgcn_s_setprio(0);                                           \
  } while (0)

__global__ __launch_bounds__(512, 2) void gemm_logits_8ph(
    const __bf16* __restrict__ A, const __bf16* __restrict__ Wb,
    float* __restrict__ Cf, const float* __restrict__ bias,
    float2* __restrict__ part) {
  __shared__ __align__(16) char smem[131072];

  const int tid = threadIdx.x;
  // T1 bijective XCD swizzle: grid (8,125), nwg=1000 % 8 == 0.
  int h = blockIdx.y * 8 + blockIdx.x;
  h = (h & 7) * 125 + (h >> 3);
  const int bx = h & 7, by = h >> 3;
  const int m0 = bx * 256, n0 = by * 256;

  const int lane = tid & 63, wave = tid >> 6;
  const int wr = wave >> 2, wc = wave & 3;     // 2M x 4N waves
  const int lrow = lane & 15, quad = lane >> 4;

  // frag-read bases (byte offsets into a 64KB buffer half)
  const int aRow  = (wr * 128 + lrow) * 128;
  const int bRow  = (wc * 64 + lrow) * 128;
  const int lsw   = (lrow & 7) << 4;
  const int cksw0 = (quad * 16) ^ lsw;         // kslice 0
  const int cksw1 = (64 + quad * 16) ^ lsw;    // kslice 1

  // staging: thread covers chunk row = base + (tid>>3), 16B slot ci = tid&7.
  // Pre-swizzled source column: cix = ci ^ (row&7).
  const int t8  = tid >> 3;
  const int cix = (tid & 7) ^ (t8 & 7);
  const __bf16* gA00 = A + (size_t)(m0 + t8) * 1024 + cix * 8;
  const __bf16* gA01 = A + (size_t)(m0 + 128 + t8) * 1024 + cix * 8;
  const __bf16* gA10 = gA00 + 64 * 1024;
  const __bf16* gA11 = gA01 + 64 * 1024;
  const __bf16* gB00 = Wb + (size_t)(n0 + t8) * 1024 + cix * 8;
  const __bf16* gB01 = Wb + (size_t)(n0 + 64 + t8) * 1024 + cix * 8;
  const __bf16* gB10 = gB00 + 128 * 1024;
  const __bf16* gB11 = gB01 + 128 * 1024;

  floatx4 acc[8][4] = {};
  bf16x8 aF[4], bB[4];

  // prologue: stage tile 0 into buf0, order A0,B*,A1 (first 6 = P1's needs).
  gl_lds16(gA00, (__bf16*)(smem + tid * 16));
  gl_lds16(gA01, (__bf16*)(smem + 16384 + tid * 16));
  gl_lds16(gB00, (__bf16*)(smem + 32768 + tid * 16));
  gl_lds16(gB01, (__bf16*)(smem + 40960 + tid * 16));
  gl_lds16(gB10, (__bf16*)(smem + 49152 + tid * 16));
  gl_lds16(gB11, (__bf16*)(smem + 57344 + tid * 16));
  gl_lds16(gA10, (__bf16*)(smem + 8192 + tid * 16));
  gl_lds16(gA11, (__bf16*)(smem + 24576 + tid * 16));
  VMCNT(2);   // A0 + all B resident; A1 still in flight
  SBAR();

  for (int t = 0; t < 15; ++t) {
    char* cb = smem + (t & 1) * 65536;
    char* nb = smem + ((t & 1) ^ 1) * 65536;
    const int ke = (t + 1) * 64;
    // P1 (mh0,k0): stage A0', B0'
    LDB(0); LDA(0, 0);
    gl_lds16(gA00 + ke, (__bf16*)(nb + tid * 16));
    gl_lds16(gA01 + ke, (__bf16*)(nb + 16384 + tid * 16));
    gl_lds16(gB00 + ke, (__bf16*)(nb + 32768 + tid * 16));
    gl_lds16(gB01 + ke, (__bf16*)(nb + 40960 + tid * 16));
    SBAR(); LGK0();
    MM(0);
    VMCNT(4); SBAR();         // retire A1^t (2-phase margin), publish for P2
    // P2 (mh1,k0): stage B1'
    LDA(1, 0);
    gl_lds16(gB10 + ke, (__bf16*)(nb + 49152 + tid * 16));
    gl_lds16(gB11 + ke, (__bf16*)(nb + 57344 + tid * 16));
    SBAR(); LGK0();
    MM(1);
    SBAR();
    // P3 (mh0,k1): stage A1'
    LDB(1); LDA(0, 1);
    gl_lds16(gA10 + ke, (__bf16*)(nb + 8192 + tid * 16));
    gl_lds16(gA11 + ke, (__bf16*)(nb + 24576 + tid * 16));
    SBAR(); LGK0();
    MM(0);
    SBAR();
    // P4 (mh1,k1): no stage
    LDA(1, 1);
    SBAR(); LGK0();
    MM(1);
    VMCNT(2); SBAR();         // retire A0',B0',B1' (youngest 2-phase margin)
  }
  {  // last K-tile (buf1): only A1^15 outstanding; drain it before mh1.
    char* cb = smem + 65536;
    LDB(0); LDA(0, 0); MM(0);
    VMCNT(0); SBAR();
    LDA(1, 0); MM(1);
    LDB(1); LDA(0, 1); MM(0);
    LDA(1, 1); MM(1);
  }

  // ---- epilogue (r3 HW-proven): bias add, C store, softmax partials -----
  // C/D layout: col = lane&15, row = quad*4 + reg  [m89-verified]
  float bv[4];
#pragma unroll
  for (int nj = 0; nj < 4; ++nj) bv[nj] = bias[n0 + wc * 64 + nj * 16 + lrow];

  // reduction scratch aliases buf0 (dead: tile 15 lives in buf1)
  float* pm = (float*)smem;
  float* ps = (float*)(smem + 4096);

#pragma unroll
  for (int mi = 0; mi < 8; ++mi) {
    const int rowb = wr * 128 + mi * 16 + quad * 4;
#pragma unroll
    for (int r = 0; r < 4; ++r) {
      const float v0 = acc[mi][0][r] + bv[0];
      const float v1 = acc[mi][1][r] + bv[1];
      const float v2 = acc[mi][2][r] + bv[2];
      const float v3 = acc[mi][3][r] + bv[3];
      const size_t rb = (size_t)(m0 + rowb + r) * V_DIM + n0 + wc * 64 + lrow;
      Cf[rb]      = v0;
      Cf[rb + 16] = v1;
      Cf[rb + 32] = v2;
      Cf[rb + 48] = v3;
      float mx = fmaxf(fmaxf(v0, v1), fmaxf(v2, v3));
#pragma unroll
      for (int msk = 1; msk < 16; msk <<= 1)
        mx = fmaxf(mx, __shfl_xor(mx, msk, 64));
      float sm = __expf(v0 - mx) + __expf(v1 - mx) + __expf(v2 - mx) +
                 __expf(v3 - mx);
#pragma unroll
      for (int msk = 1; msk < 16; msk <<= 1) sm += __shfl_xor(sm, msk, 64);
      if (lrow == 0) {
        pm[(rowb + r) * 4 + wc] = mx;
        ps[(rowb + r) * 4 + wc] = sm;
      }
    }
  }
  __syncthreads();
  if (tid < 256) {
    float m = pm[tid * 4], s = ps[tid * 4];
#pragma unroll
    for (int w = 1; w < 4; ++w) {
      const float om = pm[tid * 4 + w], os = ps[tid * 4 + w];
      const float nm = fmaxf(m, om);
      s = s * __expf(m - nm) + os * __expf(om - nm);
      m = nm;
    }
    part[(size_t)(m0 + tid) * gridDim.y + by] = make_float2(m, s);
  }
}

// ---------------------------------------------------------------------------
// Tree-level GEMM: gh[M,6144] = h[M,1024] * Whh[6144,1024]^T (all bf16).
// Tile 128x64, 256 thr (4 waves stacked in M), BK=32.
// Depth-2 prefetch, 3-buffer round-robin, counted VMCNT(3) + RAW barrier
// (r10-measured: -50us vs 2-phase dbuf across the 5-level tree stack).
// Ledger (per wave): enter iter t with 6 outstanding (tiles t, t+1);
// VMCNT(3) retires tile t's 3; SBAR -> whole tile resident. Write-after-read:
// buf (t+2)%3 was read at iter t-1; those ds_reads complete before each
// wave's MFMAs (compiler lgkmcnt), hence before iter t's SBAR; TSTAGE is
// issued after the SBAR. W split left|right at n=3072.
// ---------------------------------------------------------------------------
__global__ __launch_bounds__(256) void gemm_tree(
    const __bf16* __restrict__ A, const __bf16* __restrict__ Wb0,
    const __bf16* __restrict__ Wb1, __bf16* __restrict__ Cb, int M) {
  constexpr int K = H_DIM;
  __shared__ __align__(16) __bf16 As[3][128 * 32];
  __shared__ __align__(16) __bf16 Bs[3][64 * 32];

  const int tid = threadIdx.x;
  const int nbx = gridDim.x;
  const int nwg = nbx * gridDim.y;
  int hflat = blockIdx.y * nbx + blockIdx.x;
  if ((nwg & 7) == 0) {
    const int cpx = nwg >> 3;
    hflat = (hflat & 7) * cpx + (hflat >> 3);
  }
  const int bx = hflat % nbx;
  const int by = hflat / nbx;
  const int m0 = bx * 128;
  const int n0 = by * 64;
  const int lane = tid & 63, wave = tid >> 6;
  const int lrow = lane & 15, quad = lane >> 4;
  const int wm = wave * 32;

  const __bf16* Wb = Wb0;
  int nw0 = n0;
  if (n0 >= 3072) { Wb = Wb1; nw0 = n0 - 3072; }

  const int sr = tid >> 2;       // 0..63
  const int sk = (tid & 3) * 8;  // 0,8,16,24
  int ra0 = m0 + sr;      if (ra0 >= M) ra0 = M - 1;  // clamp (small M)
  int ra1 = m0 + sr + 64; if (ra1 >= M) ra1 = M - 1;
  const __bf16* ga0 = A + (size_t)ra0 * K + sk;
  const __bf16* ga1 = A + (size_t)ra1 * K + sk;
  const __bf16* gb0 = Wb + (size_t)(nw0 + sr) * K + sk;

  floatx4 acc[2][4] = {};

#define TSTAGE(T, BUF)                                     \
  do {                                                     \
    gl_lds16(ga0 + (T) * 32, As[BUF] + tid * 8);           \
    gl_lds16(ga1 + (T) * 32, As[BUF] + 2048 + tid * 8);    \
    gl_lds16(gb0 + (T) * 32, Bs[BUF] + tid * 8);           \
  } while (0)
#define TCOMP(CB)                                                            \
  do {                                                                       \
    bf16x8 af[2], bfr[4];                                                    \
    _Pragma("unroll") for (int i = 0; i < 2; i++)                            \
        af[i] = *(const bf16x8*)(&As[CB][(wm + i * 16 + lrow) * 32 +         \
                                         quad * 8]);                         \
    _Pragma("unroll") for (int j = 0; j < 4; j++)                            \
        bfr[j] = *(const bf16x8*)(&Bs[CB][(j * 16 + lrow) * 32 + quad * 8]); \
    _Pragma("unroll") for (int i = 0; i < 2; i++)                            \
        _Pragma("unroll") for (int j = 0; j < 4; j++)                        \
            acc[i][j] = __builtin_amdgcn_mfma_f32_16x16x32_bf16(             \
                af[i], bfr[j], acc[i][j], 0, 0, 0);                          \
  } while (0)

  TSTAGE(0, 0);
  TSTAGE(1, 1);
  for (int t = 0; t < 31; ++t) {
    VMCNT(3);          // tile t resident (tile t+1's 3 loads stay in flight)
    SBAR();            // all waves retired tile t; buf (t+2)%3 free
    if (t + 2 < 32) TSTAGE(t + 2, (t + 2) % 3);
    TCOMP(t % 3);
  }
  VMCNT(0);
  SBAR();
  TCOMP(31 % 3);
#undef TSTAGE
#undef TCOMP

  // C/D layout: col = lane&15, row = quad*4 + reg
#pragma unroll
  for (int i = 0; i < 2; i++) {
#pragma unroll
    for (int j = 0; j < 4; j++) {
      const int col = n0 + j * 16 + lrow;
#pragma unroll
      for (int r = 0; r < 4; r++) {
        const int row = m0 + wm + i * 16 + quad * 4 + r;
        if (row < M) Cb[(size_t)row * 6144 + col] = (__bf16)acc[i][j][r];
      }
    }
  }
}

// ---------------------------------------------------------------------------
// NT GEMM fallback (logits path when ws too small for bf16 W_out).
// ---------------------------------------------------------------------------
template <int TN, bool LOGITS, bool WBF16>
__global__ __launch_bounds__(256) void gemm_nt(
    const __bf16* __restrict__ A, const __bf16* __restrict__ Wb0,
    const __bf16* __restrict__ Wb1, const float* __restrict__ Wf,
    __bf16* __restrict__ Cb, float* __restrict__ Cf,
    const float* __restrict__ bias, float2* __restrict__ part, int M, int N) {
  constexpr int K = H_DIM;
  constexpr int MI = (TN == 128) ? 4 : 2;
  __shared__ __align__(16) __bf16 As[128 * 32];
  __shared__ __align__(16) __bf16 Bs[TN * 32];

  const int tid  = threadIdx.x;
  const int nbx = gridDim.x;
  const int nwg = nbx * gridDim.y;
  int hflat = blockIdx.y * nbx + blockIdx.x;
  if ((nwg & 7) == 0) {
    const int cpx = nwg >> 3;
    hflat = (hflat & 7) * cpx + (hflat >> 3);
  }
  const int bx = hflat % nbx;
  const int by = hflat / nbx;
  const int m0   = bx * 128;
  const int n0   = by * TN;
  const int lane = tid & 63;
  const int wave = tid >> 6;
  const int lrow = lane & 15;
  const int quad = lane >> 4;
  const int wm   = (TN == 128) ? (wave >> 1) * 64 : wave * 32;
  const int wn   = (TN == 128) ? (wave & 1) * 64 : 0;

  const __bf16* Wb = Wb0;
  int nw0 = n0;
  if (!LOGITS && n0 >= 3072) { Wb = Wb1; nw0 = n0 - 3072; }

  const int sr = tid >> 2;
  const int sk = (tid & 3) * 8;

  int ra0 = m0 + sr;      if (ra0 >= M) ra0 = M - 1;
  int ra1 = m0 + sr + 64; if (ra1 >= M) ra1 = M - 1;
  const __bf16* ga0 = A + (size_t)ra0 * K + sk;
  const __bf16* ga1 = A + (size_t)ra1 * K + sk;
  const __bf16* gb0 = nullptr; const __bf16* gb1 = nullptr;
  const float* gf0 = nullptr; const float* gf1 = nullptr;
  if (WBF16) {
    gb0 = Wb + (size_t)(nw0 + sr) * K + sk;
    if (TN == 128) gb1 = Wb + (size_t)(nw0 + sr + 64) * K + sk;
  } else {
    gf0 = Wf + (size_t)(n0 + sr) * K + sk;
    gf1 = Wf + (size_t)(n0 + sr + 64) * K + sk;
  }

  floatx4 acc[MI][4] = {};

  for (int kt = 0; kt < K; kt += 32) {
    float4 w00, w01, w10, w11;
    if (!WBF16) {
      w00 = *(const float4*)(gf0 + kt);
      w01 = *(const float4*)(gf0 + kt + 4);
      w10 = *(const float4*)(gf1 + kt);
      w11 = *(const float4*)(gf1 + kt + 4);
    }
    __syncthreads();
    gl_lds16(ga0 + kt, As + tid * 8);
    gl_lds16(ga1 + kt, As + 2048 + tid * 8);
    if (WBF16) {
      gl_lds16(gb0 + kt, Bs + tid * 8);
      if (TN == 128) gl_lds16(gb1 + kt, Bs + 2048 + tid * 8);
    } else {
      *(bf16x8*)(&Bs[sr * 32 + sk])        = cvt8(w00, w01);
      *(bf16x8*)(&Bs[(sr + 64) * 32 + sk]) = cvt8(w10, w11);
    }
    __syncthreads();

    bf16x8 af[MI], bfr[4];
#pragma unroll
    for (int i = 0; i < MI; i++)
      af[i] = *(const bf16x8*)(&As[(wm + i * 16 + lrow) * 32 + quad * 8]);
#pragma unroll
    for (int j = 0; j < 4; j++)
      bfr[j] = *(const bf16x8*)(&Bs[(wn + j * 16 + lrow) * 32 + quad * 8]);
#pragma unroll
    for (int i = 0; i < MI; i++)
#pragma unroll
      for (int j = 0; j < 4; j++)
        acc[i][j] =
            __builtin_amdgcn_mfma_f32_16x16x32_bf16(af[i], bfr[j], acc[i][j], 0, 0, 0);
  }

  float bv[4];
  if constexpr (LOGITS) {
#pragma unroll
    for (int j = 0; j < 4; j++) bv[j] = bias[n0 + wn + j * 16 + lrow];
  }
#pragma unroll
  for (int i = 0; i < MI; i++) {
#pragma unroll
    for (int j = 0; j < 4; j++) {
      const int col = n0 + wn + j * 16 + lrow;
#pragma unroll
      for (int r = 0; r < 4; r++) {
        const int row = m0 + wm + i * 16 + quad * 4 + r;
        if (row < M) {
          if (LOGITS) Cf[(size_t)row * N + col] = acc[i][j][r] + bv[j];
          else        Cb[(size_t)row * N + col] = (__bf16)acc[i][j][r];
        }
      }
    }
  }

  if constexpr (LOGITS) {
    __shared__ float pmax[2][128], psum[2][128];
    const int wnh = wn >> 6;
#pragma unroll
    for (int i = 0; i < MI; i++) {
#pragma unroll
      for (int r = 0; r < 4; r++) {
        float mx = -3.0e38f;
#pragma unroll
        for (int j = 0; j < 4; j++) mx = fmaxf(mx, acc[i][j][r] + bv[j]);
#pragma unroll
        for (int mask = 1; mask < 16; mask <<= 1)
          mx = fmaxf(mx, __shfl_xor(mx, mask, 64));
        float sm = 0.f;
#pragma unroll
        for (int j = 0; j < 4; j++) sm += __expf(acc[i][j][r] + bv[j] - mx);
#pragma unroll
        for (int mask = 1; mask < 16; mask <<= 1)
          sm += __shfl_xor(sm, mask, 64);
        if (lrow == 0) {
          pmax[wnh][wm + i * 16 + quad * 4 + r] = mx;
          psum[wnh][wm + i * 16 + quad * 4 + r] = sm;
        }
      }
    }
    __syncthreads();
    if (tid < 128) {
      const float ma = pmax[0][tid], mb = pmax[1][tid];
      const float nm = fmaxf(ma, mb);
      const float ns = psum[0][tid] * __expf(ma - nm) +
                       psum[1][tid] * __expf(mb - nm);
      part[(size_t)(m0 + tid) * gridDim.y + by] = make_float2(nm, ns);
    }
  }
}

// ---------------------------------------------------------------------------
// GRU gates from gh (M x 6144 bf16, [left 3H | right 3H], no biases in gh).
// Vectorized x4 (G13). grid = (M), block 256, thread handles 4 cols.
// children interleaved: left -> 2j, right -> 2j+1.
// ---------------------------------------------------------------------------
__global__ __launch_bounds__(256) void gru_gate(
    const __bf16* __restrict__ gh, const float* __restrict__ bih_l,
    const float* __restrict__ bhh_l, const float* __restrict__ bih_r,
    const float* __restrict__ bhh_r, const __bf16* __restrict__ hin,
    __bf16* __restrict__ hout, int n) {
  const int row = blockIdx.x;
  const int c = threadIdx.x * 4;
  const int b = row / n, j = row - b * n;
  const size_t g6 = (size_t)row * 6144;
  const bf16x4 h4 = *(const bf16x4*)(hin + (size_t)row * H_DIM + c);
  const size_t obase = (size_t)(b * 2 * n + 2 * j) * H_DIM;

  bf16x4 og[2];
#pragma unroll
  for (int side = 0; side < 2; ++side) {
    const float* bih = side ? bih_r : bih_l;
    const float* bhh = side ? bhh_r : bhh_l;
    const size_t gb = g6 + side * 3072;
    const bf16x4 g0 = *(const bf16x4*)(gh + gb + c);
    const bf16x4 g1 = *(const bf16x4*)(gh + gb + 1024 + c);
    const bf16x4 g2 = *(const bf16x4*)(gh + gb + 2048 + c);
    const float4 br0 = *(const float4*)(bih + c);
    const float4 br1 = *(const float4*)(bih + 1024 + c);
    const float4 br2 = *(const float4*)(bih + 2048 + c);
    const float4 bh0 = *(const float4*)(bhh + c);
    const float4 bh1 = *(const float4*)(bhh + 1024 + c);
    const float4 bh2 = *(const float4*)(bhh + 2048 + c);
    const float* pr0 = (const float*)&br0; const float* ph0 = (const float*)&bh0;
    const float* pr1 = (const float*)&br1; const float* ph1 = (const float*)&bh1;
    const float* pr2 = (const float*)&br2; const float* ph2 = (const float*)&bh2;
    bf16x4 o;
#pragma unroll
    for (int e = 0; e < 4; ++e) {
      const float gr = (float)g0[e] + ph0[e];
      const float gz = (float)g1[e] + ph1[e];
      const float gn = (float)g2[e] + ph2[e];
      const float r = 1.f / (1.f + __expf(-(pr0[e] + gr)));
      const float z = 1.f / (1.f + __expf(-(pr1[e] + gz)));
      const float nn = tanhf(pr2[e] + r * gn);
      o[e] = (__bf16)((1.f - z) * nn + z * (float)h4[e]);
    }
    og[side] = o;
  }
  *(bf16x4*)(hout + obase + c) = og[0];
  *(bf16x4*)(hout + obase + H_DIM + c) = og[1];
}

// ---------------------------------------------------------------------------
// log_softmax finish: reduce NB per-row (max,sum) partials, then one RMW pass.
// ---------------------------------------------------------------------------
__global__ __launch_bounds__(256) void lsm_finish(
    float* __restrict__ out, const float2* __restrict__ part, int nb) {
  const int row = blockIdx.x;
  const int tid = threadIdx.x;

  float m = -3.0e38f, s = 0.f;
  if (tid < nb) {
    const float2 p = part[(size_t)row * nb + tid];
    m = p.x; s = p.y;
  }
#pragma unroll
  for (int off = 32; off; off >>= 1) {
    float om = __shfl_xor(m, off, 64);
    float os = __shfl_xor(s, off, 64);
    float nm = fmaxf(m, om);
    s = s * __expf(m - nm) + os * __expf(om - nm);
    m = nm;
  }
  __shared__ float rm[4], rs[4];
  if ((tid & 63) == 0) { rm[tid >> 6] = m; rs[tid >> 6] = s; }
  __syncthreads();
  const float M4 = fmaxf(fmaxf(rm[0], rm[1]), fmaxf(rm[2], rm[3]));
  const float S4 = rs[0] * __expf(rm[0] - M4) + rs[1] * __expf(rm[1] - M4) +
                   rs[2] * __expf(rm[2] - M4) + rs[3] * __expf(rm[3] - M4);
  const float lg = M4 + __logf(S4);

  float4* p4 = (float4*)(out + (size_t)row * V_DIM);
  for (int i = tid; i < 8000; i += 256) {
    float4 v = p4[i];
    v.x -= lg; v.y -= lg; v.z -= lg; v.w -= lg;
    p4[i] = v;
  }
}

// ---------------------------------------------------------------------------
extern "C" void kernel_launch(void* const* d_in, const int* in_sizes, int n_in,
                              void* d_out, int out_size, void* d_ws,
                              size_t ws_size, hipStream_t stream) {
  const float* enc   = (const float*)d_in[0];
  const float* Whh_l = (const float*)d_in[1];
  const float* bih_l = (const float*)d_in[2];
  const float* bhh_l = (const float*)d_in[3];
  const float* Whh_r = (const float*)d_in[4];
  const float* bih_r = (const float*)d_in[5];
  const float* bhh_r = (const float*)d_in[6];
  const float* W_out = (const float*)d_in[7];
  const float* b_out = (const float*)d_in[8];
  float* out = (float*)d_out;

  char* ws = (char*)d_ws;
  __bf16* ghb    = (__bf16*)ws;                          // 12,582,912
  __bf16* buf0   = (__bf16*)(ws + 12582912);             // 4 MB
  __bf16* buf1   = (__bf16*)(ws + 16777216);             // 4 MB
  __bf16* WhhB_l = (__bf16*)(ws + 20971520);             // 6,291,456
  __bf16* WhhB_r = WhhB_l + 3145728;                     // 6,291,456
  __bf16* encB   = (__bf16*)(ws + 33554432);             // 131,072
  __bf16* WoutB  = (__bf16*)(ws + 33685504);             // 65,536,000
  float2* part   = (float2*)ghb;                         // ghb dead by logits
  const bool big = ws_size >= (size_t)(33685504 + 65536000);

  f2b<<<256, 256, 0, stream>>>(Whh_l, WhhB_l, 3 * H_DIM * H_DIM);
  f2b<<<256, 256, 0, stream>>>(Whh_r, WhhB_r, 3 * H_DIM * H_DIM);
  f2b<<<64, 256, 0, stream>>>(enc, encB, B_DIM * H_DIM);
  if (big) f2b<<<1024, 256, 0, stream>>>(W_out, WoutB, V_DIM * H_DIM);

  const __bf16* cur = encB;
  __bf16* nxt = buf0;
  int n = 1;
  for (int d = 0; d < DEPTH_C; d++) {
    const int M = B_DIM * n;
    dim3 gg((M + 127) / 128, 6144 / 64);
    gemm_tree<<<gg, 256, 0, stream>>>(cur, WhhB_l, WhhB_r, ghb, M);
    gru_gate<<<dim3(M), 256, 0, stream>>>(ghb, bih_l, bhh_l, bih_r, bhh_r,
                                          cur, nxt, n);
    cur = nxt;
    nxt = (nxt == buf0) ? buf1 : buf0;
    n *= 2;
  }

  // logits = cur(2048x1024 bf16) @ W_out^T + b_out -> d_out fp32 (+ partials)
  if (big) {
    gemm_logits_8ph<<<dim3(8, 125), 512, 0, stream>>>(cur, WoutB, out, b_out,
                                                      part);
    lsm_finish<<<2048, 256, 0, stream>>>(out, part, 125);
  } else {
    dim3 gf(2048 / 128, V_DIM / 128);
    gemm_nt<128, true, false><<<gf, 256, 0, stream>>>(
        cur, nullptr, nullptr, W_out, nullptr, out, b_out, part, 2048, V_DIM);
    lsm_finish<<<2048, 256, 0, stream>>>(out, part, 250);
  }
}